// Round 2
// baseline (395.419 us; speedup 1.0000x reference)
//
#include <hip/hip_runtime.h>
#include <hip/hip_bf16.h>

// GateAttentionUnit. B=16, N=512, D=1024, E=2048, S=128, F=2E+S=4224.
// CONFIRMED: all 10 inputs fp32, output fp32. Internal compute bf16 MFMA.
//
// Pipeline:
//   K0 rope_table: cos/sin[512][64] fp32 -> d_out scratch
//   K0b cvt uv_w -> bf16 (d_out scratch); K0c cvt o_w -> bf16 (ws)
//   K1 ln:         x -> xn bf16 (d_out scratch)                    [8192 x 1024]
//   K2 gemm256<EpiUV>: silu(xn @ uv_wb^T + uv_b) -> u | vT | base  [8192 x 4224]
//   K3 rope_qk:    q,k = rope(base*gamma+beta) (d_out scratch)     [8192 x 128]
//   K4 gemm_nt<EpiQK>:   km = relu(q@k^T/512 + relpos)^2 (d_out)   [16][512][512]
//   K5 gemm256<EpiAttn>: out2 = u * (km @ vT^T), out2 aliases u    [8192 x 2048]
//   K6 gemm_nt<EpiOut>:  out = out2 @ o_wb^T + o_b + x  (fp32 out) [8192 x 1024]
//
// R8 -> R9: gemm256 rebuilt as fine-grained 8-phase-style pipeline.
// R8 post-mortem: coarse stage-clump gave depth-1 pipeline (vmcnt stall every
// iter) -> per-CU rate identical to 128^2 kernel (2.36 TF/CU), plus 3-round
// tail on 544 blocks = 170us. R9: BK=32, FOUR 32KB LDS buffers, 2 phases per
// K-tile {ds_reads + half-stage -> barrier -> setprio+16 MFMA -> barrier},
// stage tile t+3 during iter t (2-3 iters of load lead time), counted
// vmcnt(8) once per tile, raw s_barrier only (no __syncthreads in loop).
// Race-freedom: buf (t+3)&3 freed by end-of-iter-(t-1) barrier (reads
// materialize before it: MFMA consumed them); reads of tile t guarded by
// vmcnt(8)+barrier at end of iter t-1.
//
// ws (68 MiB): u [0,32M) (out2 alias), vT [32M,64M), o_wb [64M,68M)
// d_out (33.55 MB fp32) dead-interval scratch:
//   xn [0,16M) K1->K2 ; uv_wb [16.78M, 25.69M) 4352 rows (pad zeroed) ;
//   baseb [25.69M, 27.79M) ; cosT/sinT [27.79M, 28.05M) ; then qb [0,2M)
//   kb [2M,4M) K3->K4 ; km [4M,12M) K4->K5. All dead before K6 writes d_out.

typedef __bf16 bf16_t;
typedef __bf16 bf16x4 __attribute__((ext_vector_type(4)));
typedef __bf16 bf16x8 __attribute__((ext_vector_type(8)));
typedef float  f32x4  __attribute__((ext_vector_type(4)));

__device__ __forceinline__ void async16(const void* g, void* l) {
  __builtin_amdgcn_global_load_lds(
      (const __attribute__((address_space(1))) void*)g,
      (__attribute__((address_space(3))) void*)l, 16, 0, 0);
}

// ---------------- sentinel (ws guard diagnostics) ----------------
__global__ __launch_bounds__(256) void fill_const(float* __restrict__ out,
                                                  float val, int n) {
  int i = blockIdx.x * 256 + threadIdx.x;
  if (i < n) out[i] = val;
}

// ---------------- K0: rope sin/cos tables ----------------
__global__ void rope_table(float* __restrict__ cosT, float* __restrict__ sinT) {
  int idx = blockIdx.x * 256 + threadIdx.x;   // 512*64
  int n = idx >> 6, j = idx & 63;
  float invf = (float)pow(10000.0, (double)j * (1.0 / 64.0));
  float angf = (float)n * invf;
  cosT[idx] = (float)cos((double)angf);
  sinT[idx] = (float)sin((double)angf);
}

// ---------------- K0b/K0c: fp32 -> bf16 convert ----------------
__global__ __launch_bounds__(256) void cvt_f32_bf16(const float* __restrict__ in,
                                                    bf16_t* __restrict__ out,
                                                    int n4) {
  int i = blockIdx.x * 256 + threadIdx.x;
  if (i < n4) {
    f32x4 v = ((const f32x4*)in)[i];
    bf16x4 o;
    o[0] = (__bf16)v[0]; o[1] = (__bf16)v[1];
    o[2] = (__bf16)v[2]; o[3] = (__bf16)v[3];
    ((bf16x4*)out)[i] = o;
  }
}

// ---------------- K1: layernorm (fp32 in, bf16 out) ----------------
__global__ __launch_bounds__(256) void ln_kernel(const float* __restrict__ x,
                                                 const float* __restrict__ w,
                                                 const float* __restrict__ b,
                                                 bf16_t* __restrict__ xn) {
  int row = blockIdx.x;
  int tid = threadIdx.x;
  f32x4 v = *(const f32x4*)(x + (size_t)row * 1024 + tid * 4);
  float s = v[0] + v[1] + v[2] + v[3];
  float s2 = v[0]*v[0] + v[1]*v[1] + v[2]*v[2] + v[3]*v[3];
  for (int o = 32; o > 0; o >>= 1) {
    s += __shfl_down(s, o);
    s2 += __shfl_down(s2, o);
  }
  __shared__ float ps[4], ps2[4];
  if ((tid & 63) == 0) { ps[tid >> 6] = s; ps2[tid >> 6] = s2; }
  __syncthreads();
  float st = ps[0] + ps[1] + ps[2] + ps[3];
  float st2 = ps2[0] + ps2[1] + ps2[2] + ps2[3];
  float mean = st * (1.f / 1024.f);
  float var = st2 * (1.f / 1024.f) - mean * mean;
  float inv = 1.f / sqrtf(var + 1e-5f);
  bf16x4 o4;
  for (int i = 0; i < 4; i++) {
    float wn = w[tid * 4 + i], bn = b[tid * 4 + i];
    o4[i] = (__bf16)((v[i] - mean) * inv * wn + bn);
  }
  *(bf16x4*)(xn + (size_t)row * 1024 + tid * 4) = o4;
}

// ---------------- K3: gamma/beta + rope -> q, k ----------------
__global__ __launch_bounds__(128) void rope_qk(const bf16_t* __restrict__ baseb,
                                               const float* __restrict__ gamma,
                                               const float* __restrict__ beta,
                                               const float* __restrict__ cosT,
                                               const float* __restrict__ sinT,
                                               bf16_t* __restrict__ q,
                                               bf16_t* __restrict__ k) {
  int m = blockIdx.x;        // b*512 + n
  int n = m & 511;
  int s = threadIdx.x;       // 0..127
  float base = (float)baseb[(size_t)m * 128 + s];
  __shared__ float t[2][128];
  t[0][s] = base * gamma[s] + beta[s];
  t[1][s] = base * gamma[128 + s] + beta[128 + s];
  __syncthreads();
  int j = s & 63;
  float c = cosT[n * 64 + j], sn = sinT[n * 64 + j];
  for (int h = 0; h < 2; h++) {
    float x1 = t[h][j], x2 = t[h][64 + j];
    float r = (s < 64) ? (x1 * c - x2 * sn) : (x2 * c + x1 * sn);
    bf16_t* dst = h == 0 ? q : k;
    dst[(size_t)m * 128 + s] = (__bf16)r;
  }
}

// ---------------- epilogues (NaN-scrub clamps: never fire on legit data) ----
struct EpiUV {   // + uv_b, silu -> u | vT (transposed) | base
  const float* uv_b;
  bf16_t* u;
  bf16_t* vT;      // [16][2048][512]
  bf16_t* baseb;
  __device__ void operator()(int b, int m, int n, float acc) const {
    if (n >= 4224) return;   // N padded to 4352 for 256-tile
    float xv = acc + uv_b[n];
    float sv = xv / (1.f + __expf(-xv));
    sv = fminf(fmaxf(sv, -100.f), 100.f);
    if (n < 2048) {
      u[(size_t)m * 2048 + n] = (__bf16)sv;
    } else if (n < 4096) {
      int bb = m >> 9, nseq = m & 511;
      vT[((size_t)bb * 2048 + (n - 2048)) * 512 + nseq] = (__bf16)sv;
    } else {
      baseb[(size_t)m * 128 + (n - 4096)] = (__bf16)sv;
    }
  }
};
struct EpiQK {   // clamp(relu(acc/512 + w_rel[511+j-i]))^2 -> km
  const float* w_rel;
  bf16_t* km;
  __device__ void operator()(int b, int i, int j, float acc) const {
    float bias = w_rel[511 + j - i];
    float t = fmaxf(acc * (1.f / 512.f) + bias, 0.f);
    t = fminf(t, 100.f);
    km[((size_t)b * 512 + i) * 512 + j] = (__bf16)(t * t);
  }
};
struct EpiAttn { // clamp(acc * u) -> out2 (out2 aliases u element-exactly)
  const bf16_t* u;
  bf16_t* out2;
  __device__ void operator()(int b, int i, int e, float acc) const {
    size_t m = (size_t)b * 512 + i;
    float uu = (float)u[m * 2048 + e];
    float r = acc * uu;
    r = fminf(fmaxf(r, -1e6f), 1e6f);
    out2[m * 2048 + e] = (__bf16)r;
  }
};
struct EpiOut {  // clamp(acc + o_b + shortcut) -> fp32 out
  const float* o_b;
  const float* x;
  float* out;
  __device__ void operator()(int b, int m, int d, float acc) const {
    long idx = (long)m * 1024 + d;
    float r = acc + o_b[d] + x[idx];
    r = fminf(fmaxf(r, -1e5f), 1e5f);
    out[idx] = r;
  }
};

// ---------------- 128^2 NT GEMM (proven; kept for K4/K6) -------------------
template <typename Epi>
__global__ __launch_bounds__(256, 2)
void gemm_nt(const bf16_t* __restrict__ A, const bf16_t* __restrict__ Bm,
             int lda, int ldb, int K, long sAz, long sBz, Epi epi) {
  __shared__ __align__(16) char smem[32768];
  char* smA = smem;
  char* smB = smem + 16384;
  const int tid = threadIdx.x;
  const int lane = tid & 63;
  const int wid = tid >> 6;
  const int wm = wid & 1, wn = wid >> 1;
  const int quad = lane >> 4, col16 = lane & 15;
  const int srow = lane >> 3;
  const int skc = lane & 7;
  const int bz = blockIdx.z;
  const int tileM = blockIdx.x * 128;
  const int tileN = blockIdx.y * 128;
  const bf16_t* Ab = A + (size_t)bz * sAz;
  const bf16_t* Bb = Bm + (size_t)bz * sBz;

  f32x4 acc[4][4] = {};

  for (int k0 = 0; k0 < K; k0 += 64) {
#pragma unroll
    for (int c4 = 0; c4 < 4; c4++) {
      int ch = c4 * 4 + wid;
      int row = ch * 8 + srow;
      int kc = skc ^ (row & 7);
      async16(Ab + (size_t)(tileM + row) * lda + k0 + kc * 8, smA + ch * 1024);
      async16(Bb + (size_t)(tileN + row) * ldb + k0 + kc * 8, smB + ch * 1024);
    }
    __syncthreads();
#pragma unroll
    for (int kk = 0; kk < 2; kk++) {
      bf16x8 af[4], bfr[4];
      int jj = kk * 4 + quad;
#pragma unroll
      for (int t = 0; t < 4; t++) {
        int ml = wm * 64 + t * 16 + col16;
        int nl = wn * 64 + t * 16 + col16;
        af[t] = *(const bf16x8*)(smA + (size_t)ml * 128 + ((jj ^ (ml & 7)) * 16));
        bfr[t] = *(const bf16x8*)(smB + (size_t)nl * 128 + ((jj ^ (nl & 7)) * 16));
      }
#pragma unroll
      for (int mt = 0; mt < 4; mt++)
#pragma unroll
        for (int nt = 0; nt < 4; nt++)
          acc[mt][nt] = __builtin_amdgcn_mfma_f32_16x16x32_bf16(af[mt], bfr[nt], acc[mt][nt], 0, 0, 0);
    }
    __syncthreads();
  }

#pragma unroll
  for (int mt = 0; mt < 4; mt++) {
    int gm = tileM + wm * 64 + mt * 16 + quad * 4;
#pragma unroll
    for (int nt = 0; nt < 4; nt++) {
      int gn = tileN + wn * 64 + nt * 16 + col16;
#pragma unroll
      for (int r = 0; r < 4; r++) epi(bz, gm + r, gn, acc[mt][nt][r]);
    }
  }
}

// ---------------- 256^2 fine-pipelined NT GEMM (K2/K5) ---------------------
// 512 thr = 8 waves (2M x 4N), per-wave C = 128x64 (acc[8][4] f32x4).
// BK=32; LDS = 4 buffers x {A[256][32] 16KB | B[256][32] 16KB} = 128 KiB.
// LDS layout per matrix: 128-byte lines (2 rows of 32 bf16); 16B chunk g of
// line L stored at slot g^(L&7)  (g = (r&1)*4 + kc). Verified <=2-way bank
// aliasing (free) for both ds_read_b128 fragments and linear DMA writes.
// Pipeline: iter t computes buf t&3 in 2 phases; phase A stages A-half of
// tile t+3, phase B stages B-half (targets buf (t-1)&3, freed by the
// end-of-iter-(t-1) barrier). vmcnt(8) once per iter (tiles t+2,t+3 may
// remain in flight -> tile t+1 resident). NO __syncthreads in the loop.
template <typename Epi>
__global__ __launch_bounds__(512, 2)
void gemm256(const bf16_t* __restrict__ A, const bf16_t* __restrict__ Bm,
             int lda, int ldb, int K, long sAz, long sBz, Epi epi) {
  __shared__ __align__(16) char smem[131072];
  const int tid = threadIdx.x;
  const int lane = tid & 63;
  const int wid = tid >> 6;       // 0..7
  const int wr = wid & 1;         // M half (128 rows)
  const int wc = wid >> 1;        // N quarter (64 cols)
  const int quad = lane >> 4, col16 = lane & 15;
  const int bz = blockIdx.z;
  const int tileM = blockIdx.x * 256;
  const int tileN = blockIdx.y * 256;
  const bf16_t* Ab = A + (size_t)bz * sAz;
  const bf16_t* Bb = Bm + (size_t)bz * sBz;
  const int NT = K >> 5;          // K-tiles of 32

  // ---- precomputed staging geometry (2 chunks/thread per 16KB half) ----
  int r_st[2], kc_st[2], u_st[2];
#pragma unroll
  for (int i = 0; i < 2; i++) {
    int u = (tid >> 6) + (i << 3);      // wave-uniform LDS KB index 0..15
    int c = (u << 6) + lane;            // chunk 0..1023
    int line = c >> 3, slot = c & 7;
    int g = slot ^ (line & 7);
    u_st[i] = u;
    r_st[i] = (line << 1) + (g >> 2);   // source row 0..255
    kc_st[i] = g & 3;                   // source 16B chunk in row
  }

  // ---- precomputed fragment byte offsets ----
  int offA[8], offB[4];
#pragma unroll
  for (int mt = 0; mt < 8; mt++) {
    int r = wr * 128 + mt * 16 + col16;
    int line = r >> 1;
    int g = ((r & 1) << 2) | quad;
    offA[mt] = line * 128 + ((g ^ (line & 7)) << 4);
  }
#pragma unroll
  for (int nt = 0; nt < 4; nt++) {
    int r = wc * 64 + nt * 16 + col16;
    int line = r >> 1;
    int g = ((r & 1) << 2) | quad;
    offB[nt] = line * 128 + ((g ^ (line & 7)) << 4);
  }

  // stage half h (0=A, 1=B) of K-tile kt into buf kt&3 (2 async16/thread)
  auto stageHalf = [&](int kt, int h) {
    char* dst = (char*)smem + (kt & 3) * 32768 + h * 16384;
    const bf16_t* src = h ? Bb : Ab;
    const int ld = h ? ldb : lda;
    const int tb = h ? tileN : tileM;
    const int k0 = kt << 5;
#pragma unroll
    for (int i = 0; i < 2; i++) {
      async16(src + (size_t)(tb + r_st[i]) * ld + k0 + (kc_st[i] << 3),
              dst + u_st[i] * 1024);
    }
  };

  f32x4 acc[8][4] = {};

  // ---- prologue: stage tiles 0,1,2 ----
#pragma unroll
  for (int pt = 0; pt < 3; pt++) {
    if (pt < NT) { stageHalf(pt, 0); stageHalf(pt, 1); }
  }
  asm volatile("s_waitcnt vmcnt(8)" ::: "memory");   // tile 0 resident (mine)
  __builtin_amdgcn_s_barrier();                       // tile 0 resident (all)
  asm volatile("" ::: "memory");

  for (int t = 0; t < NT; t++) {
    const char* sA = (const char*)smem + (t & 3) * 32768;
    const char* sB = sA + 16384;
    bf16x8 a[4], b[4];

    // ================= phase A: C rows 0-63 (per wave) =================
#pragma unroll
    for (int i = 0; i < 4; i++) b[i] = *(const bf16x8*)(sB + offB[i]);
#pragma unroll
    for (int i = 0; i < 4; i++) a[i] = *(const bf16x8*)(sA + offA[i]);
    if (t + 3 < NT) stageHalf(t + 3, 0);
    asm volatile("" ::: "memory");
    __builtin_amdgcn_s_barrier();
    __builtin_amdgcn_s_setprio(1);
#pragma unroll
    for (int mt = 0; mt < 4; mt++)
#pragma unroll
      for (int nt = 0; nt < 4; nt++)
        acc[mt][nt] = __builtin_amdgcn_mfma_f32_16x16x32_bf16(
            a[mt], b[nt], acc[mt][nt], 0, 0, 0);
    __builtin_amdgcn_s_setprio(0);
    asm volatile("" ::: "memory");
    __builtin_amdgcn_s_barrier();

    // ================= phase B: C rows 64-127 (b[] reused) =============
#pragma unroll
    for (int i = 0; i < 4; i++) a[i] = *(const bf16x8*)(sA + offA[4 + i]);
    if (t + 3 < NT) stageHalf(t + 3, 1);
    asm volatile("" ::: "memory");
    __builtin_amdgcn_s_barrier();
    __builtin_amdgcn_s_setprio(1);
#pragma unroll
    for (int mt = 0; mt < 4; mt++)
#pragma unroll
      for (int nt = 0; nt < 4; nt++)
        acc[4 + mt][nt] = __builtin_amdgcn_mfma_f32_16x16x32_bf16(
            a[mt], b[nt], acc[4 + mt][nt], 0, 0, 0);
    __builtin_amdgcn_s_setprio(0);

    if (t + 1 < NT) {
      // tile t+1 resident: tiles t+2,t+3 (8 loads) may stay in flight
      asm volatile("s_waitcnt vmcnt(8)" ::: "memory");
      __builtin_amdgcn_s_barrier();
      asm volatile("" ::: "memory");
    }
  }

#pragma unroll
  for (int mt = 0; mt < 8; mt++) {
    int gm = tileM + wr * 128 + mt * 16 + quad * 4;
#pragma unroll
    for (int nt = 0; nt < 4; nt++) {
      int gn = tileN + wc * 64 + nt * 16 + col16;
#pragma unroll
      for (int r = 0; r < 4; r++) epi(bz, gm + r, gn, acc[mt][nt][r]);
    }
  }
}

extern "C" void kernel_launch(void* const* d_in, const int* in_sizes, int n_in,
                              void* d_out, int out_size, void* d_ws, size_t ws_size,
                              hipStream_t stream) {
  const float* x = (const float*)d_in[0];
  const float* ln_w = (const float*)d_in[1];
  const float* ln_b = (const float*)d_in[2];
  const float* uv_w = (const float*)d_in[3];
  const float* uv_b = (const float*)d_in[4];
  const float* gamma = (const float*)d_in[5];
  const float* beta = (const float*)d_in[6];
  const float* o_w = (const float*)d_in[7];
  const float* o_b = (const float*)d_in[8];
  const float* w_rel = (const float*)d_in[9];
  float* out = (float*)d_out;

  const int NOUT = 8388608;
  const size_t WS_NEEDED = 71303168;   // 68 MiB (>=69.4 MiB proven in R5)
  if (ws_size < WS_NEEDED) {
    float wsMiB = (float)(ws_size >> 20);
    fill_const<<<dim3(32768), dim3(256), 0, stream>>>(out, 1000.f + wsMiB, NOUT);
    return;
  }

  // ws: u [0,32M) (out2 alias), vT [32M,64M), o_wb [64M,68M)
  char* ws = (char*)d_ws;
  bf16_t* u = (bf16_t*)(ws + 0);
  bf16_t* out2 = u;
  bf16_t* vT = (bf16_t*)(ws + 33554432);
  bf16_t* o_wb = (bf16_t*)(ws + 67108864);
  // d_out dead-interval scratch (33.55 MB fp32 region):
  char* ob = (char*)d_out;
  bf16_t* xn = (bf16_t*)ob;                       // [0, 16,777,216)
  bf16_t* uv_wb = (bf16_t*)(ob + 16777216);       // 4352 rows: [16.78M, 25.69M)
  bf16_t* baseb = (bf16_t*)(ob + 25690112);       // [25,690,112, 27,787,264)
  float* cosT = (float*)(ob + 27787264);          // [27,787,264, 27,918,336)
  float* sinT = (float*)(ob + 27918336);          // [27,918,336, 28,049,408)
  bf16_t* qb = (bf16_t*)ob;                       // [0, 2M)   K3->K4
  bf16_t* kb = (bf16_t*)(ob + 2097152);           // [2M, 4M)  K3->K4
  bf16_t* km = (bf16_t*)(ob + 4194304);           // [4M, 12M) K4->K5

  rope_table<<<dim3(128), dim3(256), 0, stream>>>(cosT, sinT);
  cvt_f32_bf16<<<dim3(4224), dim3(256), 0, stream>>>(uv_w, uv_wb, 1081344);
  cvt_f32_bf16<<<dim3(2048), dim3(256), 0, stream>>>(o_w, o_wb, 524288);
  // zero the N-pad rows 4224..4351 of uv_wb (256 KiB = 65536 floats)
  fill_const<<<dim3(256), dim3(256), 0, stream>>>(
      (float*)(ob + 16777216 + 8650752), 0.f, 65536);
  ln_kernel<<<dim3(8192), dim3(256), 0, stream>>>(x, ln_w, ln_b, xn);
  // K2: silu(xn @ uv_wb^T + uv_b) -> u | vT | base: M=8192, N=4352(pad), K=1024
  gemm256<<<dim3(32, 17, 1), dim3(512), 0, stream>>>(
      xn, uv_wb, 1024, 1024, 1024, 0L, 0L, EpiUV{uv_b, u, vT, baseb});
  rope_qk<<<dim3(8192), dim3(128), 0, stream>>>(baseb, gamma, beta, cosT, sinT, qb, kb);
  // K4: km = relu(q@k^T/512 + bias)^2: per batch M=N=512, K=128
  gemm_nt<<<dim3(4, 4, 16), dim3(256), 0, stream>>>(
      qb, kb, 128, 128, 128, (long)512 * 128, (long)512 * 128, EpiQK{w_rel, km});
  // K5: out2 = u * (km @ v): per batch M=512, N=2048, K=512
  gemm256<<<dim3(2, 8, 16), dim3(512), 0, stream>>>(
      km, vT, 512, 512, 512, (long)512 * 512, (long)2048 * 512, EpiAttn{u, out2});
  // K6: out = out2 @ o_wb^T + o_b + x: M=8192, N=1024, K=2048
  gemm_nt<<<dim3(64, 8, 1), dim3(256), 0, stream>>>(
      out2, o_wb, 2048, 2048, 2048, 0L, 0L, EpiOut{o_b, x, out});
}

// Round 3
// 339.072 us; speedup vs baseline: 1.1662x; 1.1662x over previous
//
#include <hip/hip_runtime.h>
#include <hip/hip_bf16.h>

// GateAttentionUnit. B=16, N=512, D=1024, E=2048, S=128, F=2E+S=4224.
// CONFIRMED: all 10 inputs fp32, output fp32. Internal compute bf16 MFMA.
//
// Pipeline:
//   K0 rope_table: cos/sin[512][64] fp32 -> d_out scratch
//   K0b cvt uv_w -> bf16 (d_out scratch); K0c cvt o_w -> bf16 (ws)
//   K1 ln:         x -> xn bf16 (d_out scratch)                    [8192 x 1024]
//   K2 gemm<EpiUV>: silu(xn @ uv_wb^T + uv_b) -> u | vT | base     [8192 x 4224]
//   K3 rope_qk:    q,k = rope(base*gamma+beta) (d_out scratch)     [8192 x 128]
//   K4 gemm<EpiQK>:   km = relu(q@k^T/512 + relpos)^2 (d_out)      [16][512][512]
//   K5 gemm<EpiAttn>: out2 = u * (km @ vT^T), out2 aliases u       [8192 x 2048]
//   K6 gemm<EpiOut>:  out = out2 @ o_wb^T + o_b + x  (fp32 out)    [8192 x 1024]
//
// R9 -> R10: REVERT K2/K5 to the proven 128^2 gemm_nt (two independent 256^2
// pipeline reconstructions both landed at 170us vs 115.6 -- per-CU rate is
// bound by LDS<->MFMA serialization at 1 block/CU, not by vmcnt depth; the
// 128^2 kernel's 2 blocks/CU gets cross-block overlap for free). New in R10:
// EpiUV silu division replaced with v_rcp_f32 (compiler expands f32 '/' to
// div_scale/div_fmas/div_fixup ~10+ ops without fast-math; epilogue VALU was
// the VALUBusy 34% > MfmaUtil 27% signal on K2).
//
// ws (68 MiB; >=69.4 MiB proven available in R5):
//   u [0,32M) (K2->K5; out2 alias K5->K6), vT [32M,64M), o_wb [64M,68M)
// d_out (33.55 MB fp32) dead-interval scratch:
//   xn [0,16M) K1->K2 ; uv_wb [16M,24.65M) ; baseb [24.65M,26.25M) ; tables
//   [26.25M,26.5M) ; then qb [0,2M) kb [2M,4M) K3->K4 ; km [4M,12M) K4->K5.
//   All dead before K6 writes d_out.

typedef __bf16 bf16_t;
typedef __bf16 bf16x4 __attribute__((ext_vector_type(4)));
typedef __bf16 bf16x8 __attribute__((ext_vector_type(8)));
typedef float  f32x4  __attribute__((ext_vector_type(4)));

__device__ __forceinline__ void async16(const void* g, void* l) {
  __builtin_amdgcn_global_load_lds(
      (const __attribute__((address_space(1))) void*)g,
      (__attribute__((address_space(3))) void*)l, 16, 0, 0);
}

// ---------------- sentinel (ws guard diagnostics) ----------------
__global__ __launch_bounds__(256) void fill_const(float* __restrict__ out,
                                                  float val, int n) {
  int i = blockIdx.x * 256 + threadIdx.x;
  if (i < n) out[i] = val;
}

// ---------------- K0: rope sin/cos tables ----------------
__global__ void rope_table(float* __restrict__ cosT, float* __restrict__ sinT) {
  int idx = blockIdx.x * 256 + threadIdx.x;   // 512*64
  int n = idx >> 6, j = idx & 63;
  float invf = (float)pow(10000.0, (double)j * (1.0 / 64.0));
  float angf = (float)n * invf;
  cosT[idx] = (float)cos((double)angf);
  sinT[idx] = (float)sin((double)angf);
}

// ---------------- K0b/K0c: fp32 -> bf16 convert ----------------
__global__ __launch_bounds__(256) void cvt_f32_bf16(const float* __restrict__ in,
                                                    bf16_t* __restrict__ out,
                                                    int n4) {
  int i = blockIdx.x * 256 + threadIdx.x;
  if (i < n4) {
    f32x4 v = ((const f32x4*)in)[i];
    bf16x4 o;
    o[0] = (__bf16)v[0]; o[1] = (__bf16)v[1];
    o[2] = (__bf16)v[2]; o[3] = (__bf16)v[3];
    ((bf16x4*)out)[i] = o;
  }
}

// ---------------- K1: layernorm (fp32 in, bf16 out) ----------------
__global__ __launch_bounds__(256) void ln_kernel(const float* __restrict__ x,
                                                 const float* __restrict__ w,
                                                 const float* __restrict__ b,
                                                 bf16_t* __restrict__ xn) {
  int row = blockIdx.x;
  int tid = threadIdx.x;
  f32x4 v = *(const f32x4*)(x + (size_t)row * 1024 + tid * 4);
  float s = v[0] + v[1] + v[2] + v[3];
  float s2 = v[0]*v[0] + v[1]*v[1] + v[2]*v[2] + v[3]*v[3];
  for (int o = 32; o > 0; o >>= 1) {
    s += __shfl_down(s, o);
    s2 += __shfl_down(s2, o);
  }
  __shared__ float ps[4], ps2[4];
  if ((tid & 63) == 0) { ps[tid >> 6] = s; ps2[tid >> 6] = s2; }
  __syncthreads();
  float st = ps[0] + ps[1] + ps[2] + ps[3];
  float st2 = ps2[0] + ps2[1] + ps2[2] + ps2[3];
  float mean = st * (1.f / 1024.f);
  float var = st2 * (1.f / 1024.f) - mean * mean;
  float inv = 1.f / sqrtf(var + 1e-5f);
  bf16x4 o4;
  for (int i = 0; i < 4; i++) {
    float wn = w[tid * 4 + i], bn = b[tid * 4 + i];
    o4[i] = (__bf16)((v[i] - mean) * inv * wn + bn);
  }
  *(bf16x4*)(xn + (size_t)row * 1024 + tid * 4) = o4;
}

// ---------------- K3: gamma/beta + rope -> q, k ----------------
__global__ __launch_bounds__(128) void rope_qk(const bf16_t* __restrict__ baseb,
                                               const float* __restrict__ gamma,
                                               const float* __restrict__ beta,
                                               const float* __restrict__ cosT,
                                               const float* __restrict__ sinT,
                                               bf16_t* __restrict__ q,
                                               bf16_t* __restrict__ k) {
  int m = blockIdx.x;        // b*512 + n
  int n = m & 511;
  int s = threadIdx.x;       // 0..127
  float base = (float)baseb[(size_t)m * 128 + s];
  __shared__ float t[2][128];
  t[0][s] = base * gamma[s] + beta[s];
  t[1][s] = base * gamma[128 + s] + beta[128 + s];
  __syncthreads();
  int j = s & 63;
  float c = cosT[n * 64 + j], sn = sinT[n * 64 + j];
  for (int h = 0; h < 2; h++) {
    float x1 = t[h][j], x2 = t[h][64 + j];
    float r = (s < 64) ? (x1 * c - x2 * sn) : (x2 * c + x1 * sn);
    bf16_t* dst = h == 0 ? q : k;
    dst[(size_t)m * 128 + s] = (__bf16)r;
  }
}

// ---------------- epilogues (NaN-scrub clamps: never fire on legit data) ----
struct EpiUV {   // + uv_b, silu -> u | vT (transposed) | base
  const float* uv_b;
  bf16_t* u;
  bf16_t* vT;      // [16][2048][512]
  bf16_t* baseb;
  __device__ void operator()(int b, int m, int n, float acc) const {
    float xv = acc + uv_b[n];
    // silu via single v_rcp_f32 (R10): '/' expands to div_scale/fmas/fixup
    // (~10+ VALU) without fast-math; rcp is 1 ULP, irrelevant at bf16 out.
    float sv = xv * __builtin_amdgcn_rcpf(1.f + __expf(-xv));
    sv = fminf(fmaxf(sv, -100.f), 100.f);
    if (n < 2048) {
      u[(size_t)m * 2048 + n] = (__bf16)sv;
    } else if (n < 4096) {
      int bb = m >> 9, nseq = m & 511;
      vT[((size_t)bb * 2048 + (n - 2048)) * 512 + nseq] = (__bf16)sv;
    } else {
      baseb[(size_t)m * 128 + (n - 4096)] = (__bf16)sv;
    }
  }
};
struct EpiQK {   // clamp(relu(acc/512 + w_rel[511+j-i]))^2 -> km
  const float* w_rel;
  bf16_t* km;
  __device__ void operator()(int b, int i, int j, float acc) const {
    float bias = w_rel[511 + j - i];
    float t = fmaxf(acc * (1.f / 512.f) + bias, 0.f);
    t = fminf(t, 100.f);
    km[((size_t)b * 512 + i) * 512 + j] = (__bf16)(t * t);
  }
};
struct EpiAttn { // clamp(acc * u) -> out2 (out2 aliases u element-exactly)
  const bf16_t* u;
  bf16_t* out2;
  __device__ void operator()(int b, int i, int e, float acc) const {
    size_t m = (size_t)b * 512 + i;
    float uu = (float)u[m * 2048 + e];
    float r = acc * uu;
    r = fminf(fmaxf(r, -1e6f), 1e6f);
    out2[m * 2048 + e] = (__bf16)r;
  }
};
struct EpiOut {  // clamp(acc + o_b + shortcut) -> fp32 out
  const float* o_b;
  const float* x;
  float* out;
  __device__ void operator()(int b, int m, int d, float acc) const {
    long idx = (long)m * 1024 + d;
    float r = acc + o_b[d] + x[idx];
    r = fminf(fmaxf(r, -1e5f), 1e5f);
    out[idx] = r;
  }
};

// ---------------- templated NT GEMM (async-staged, XOR-swizzled LDS) -------
// C[m][n] = sum_k A[m][k]*B[n][k]; A,B bf16 K-contiguous. 128x128 tile /
// 256 threads (4 waves 2x2), BK=64, mfma_f32_16x16x32_bf16.
// LDS: 128 rows x 64 bf16 per matrix; k-chunk c of row r at 16B slot c^(r&7).
// Staging lane l=(srow,skc) fetches global chunk skc^(row&7) into slot skc.
// Fragment read: chunk jj of row ml at ml*128 + ((jj^(ml&7))*16) -> 2-way bank
// alias (free; R6 measured SQ_LDS_BANK_CONFLICT = 0).
template <typename Epi>
__global__ __launch_bounds__(256, 2)
void gemm_nt(const bf16_t* __restrict__ A, const bf16_t* __restrict__ Bm,
             int lda, int ldb, int K, long sAz, long sBz, Epi epi) {
  __shared__ __align__(16) char smem[32768];
  char* smA = smem;
  char* smB = smem + 16384;
  const int tid = threadIdx.x;
  const int lane = tid & 63;
  const int wid = tid >> 6;
  const int wm = wid & 1, wn = wid >> 1;
  const int quad = lane >> 4, col16 = lane & 15;
  const int srow = lane >> 3;   // row within 8-row chunk
  const int skc = lane & 7;     // LDS 16B slot within row
  const int bz = blockIdx.z;
  const int tileM = blockIdx.x * 128;
  const int tileN = blockIdx.y * 128;
  const bf16_t* Ab = A + (size_t)bz * sAz;
  const bf16_t* Bb = Bm + (size_t)bz * sBz;

  f32x4 acc[4][4] = {};

  for (int k0 = 0; k0 < K; k0 += 64) {
#pragma unroll
    for (int c4 = 0; c4 < 4; c4++) {
      int ch = c4 * 4 + wid;     // wave-uniform chunk id (16 x 1KB per matrix)
      int row = ch * 8 + srow;
      int kc = skc ^ (row & 7);  // fetch chunk kc so LDS slot skc holds it
      async16(Ab + (size_t)(tileM + row) * lda + k0 + kc * 8, smA + ch * 1024);
      async16(Bb + (size_t)(tileN + row) * ldb + k0 + kc * 8, smB + ch * 1024);
    }
    __syncthreads();
#pragma unroll
    for (int kk = 0; kk < 2; kk++) {
      bf16x8 af[4], bfr[4];
      int jj = kk * 4 + quad;
#pragma unroll
      for (int t = 0; t < 4; t++) {
        int ml = wm * 64 + t * 16 + col16;
        int nl = wn * 64 + t * 16 + col16;
        af[t] = *(const bf16x8*)(smA + (size_t)ml * 128 + ((jj ^ (ml & 7)) * 16));
        bfr[t] = *(const bf16x8*)(smB + (size_t)nl * 128 + ((jj ^ (nl & 7)) * 16));
      }
#pragma unroll
      for (int mt = 0; mt < 4; mt++)
#pragma unroll
        for (int nt = 0; nt < 4; nt++)
          acc[mt][nt] = __builtin_amdgcn_mfma_f32_16x16x32_bf16(af[mt], bfr[nt], acc[mt][nt], 0, 0, 0);
    }
    __syncthreads();
  }

#pragma unroll
  for (int mt = 0; mt < 4; mt++) {
    int gm = tileM + wm * 64 + mt * 16 + quad * 4;
#pragma unroll
    for (int nt = 0; nt < 4; nt++) {
      int gn = tileN + wn * 64 + nt * 16 + col16;
#pragma unroll
      for (int r = 0; r < 4; r++) epi(bz, gm + r, gn, acc[mt][nt][r]);
    }
  }
}

extern "C" void kernel_launch(void* const* d_in, const int* in_sizes, int n_in,
                              void* d_out, int out_size, void* d_ws, size_t ws_size,
                              hipStream_t stream) {
  const float* x = (const float*)d_in[0];
  const float* ln_w = (const float*)d_in[1];
  const float* ln_b = (const float*)d_in[2];
  const float* uv_w = (const float*)d_in[3];
  const float* uv_b = (const float*)d_in[4];
  const float* gamma = (const float*)d_in[5];
  const float* beta = (const float*)d_in[6];
  const float* o_w = (const float*)d_in[7];
  const float* o_b = (const float*)d_in[8];
  const float* w_rel = (const float*)d_in[9];
  float* out = (float*)d_out;

  const int NOUT = 8388608;
  const size_t WS_NEEDED = 71303168;   // 68 MiB (>=69.4 MiB proven in R5)
  if (ws_size < WS_NEEDED) {
    float wsMiB = (float)(ws_size >> 20);
    fill_const<<<dim3(32768), dim3(256), 0, stream>>>(out, 1000.f + wsMiB, NOUT);
    return;
  }

  // ws: u [0,32M) (out2 alias), vT [32M,64M), o_wb [64M,68M)
  char* ws = (char*)d_ws;
  bf16_t* u = (bf16_t*)(ws + 0);
  bf16_t* out2 = u;
  bf16_t* vT = (bf16_t*)(ws + 33554432);
  bf16_t* o_wb = (bf16_t*)(ws + 67108864);
  // d_out dead-interval scratch (33.55 MB fp32 region):
  char* ob = (char*)d_out;
  bf16_t* xn = (bf16_t*)ob;                       // [0, 16,777,216)
  bf16_t* uv_wb = (bf16_t*)(ob + 16777216);       // [16,777,216, 25,427,968)
  bf16_t* baseb = (bf16_t*)(ob + 25427968);       // [25,427,968, 27,525,120)
  float* cosT = (float*)(ob + 27525120);          // [27,525,120, 27,656,192)
  float* sinT = (float*)(ob + 27656192);          // [27,656,192, 27,787,264)
  bf16_t* qb = (bf16_t*)ob;                       // [0, 2M)   K3->K4
  bf16_t* kb = (bf16_t*)(ob + 2097152);           // [2M, 4M)  K3->K4
  bf16_t* km = (bf16_t*)(ob + 4194304);           // [4M, 12M) K4->K5

  rope_table<<<dim3(128), dim3(256), 0, stream>>>(cosT, sinT);
  cvt_f32_bf16<<<dim3(4224), dim3(256), 0, stream>>>(uv_w, uv_wb, 1081344);
  cvt_f32_bf16<<<dim3(2048), dim3(256), 0, stream>>>(o_w, o_wb, 524288);
  ln_kernel<<<dim3(8192), dim3(256), 0, stream>>>(x, ln_w, ln_b, xn);
  // K2: silu(xn @ uv_wb^T + uv_b) -> u | vT | base: M=8192, N=4224, K=1024
  gemm_nt<<<dim3(64, 33, 1), dim3(256), 0, stream>>>(
      xn, uv_wb, 1024, 1024, 1024, 0L, 0L, EpiUV{uv_b, u, vT, baseb});
  rope_qk<<<dim3(8192), dim3(128), 0, stream>>>(baseb, gamma, beta, cosT, sinT, qb, kb);
  // K4: km = relu(q@k^T/512 + bias)^2: per batch M=N=512, K=128
  gemm_nt<<<dim3(4, 4, 16), dim3(256), 0, stream>>>(
      qb, kb, 128, 128, 128, (long)512 * 128, (long)512 * 128, EpiQK{w_rel, km});
  // K5: out2 = u * (km @ v): per batch M=512, N=2048, K=512
  gemm_nt<<<dim3(4, 16, 16), dim3(256), 0, stream>>>(
      km, vT, 512, 512, 512, (long)512 * 512, (long)2048 * 512, EpiAttn{u, out2});
  // K6: out = out2 @ o_wb^T + o_b + x: M=8192, N=1024, K=2048
  gemm_nt<<<dim3(64, 8, 1), dim3(256), 0, stream>>>(
      out2, o_wb, 2048, 2048, 2048, 0L, 0L, EpiOut{o_b, x, out});
}